// Round 5
// baseline (110.464 us; speedup 1.0000x reference)
//
#include <hip/hip_runtime.h>
#include <hip/hip_bf16.h>

// LocalCausalAttention: B=2, N=2048, D=1024, H=16, DH=64, WINDOW=64
// out = ( softmax(mask(QK^T*0.125)) V ) Wout^T + bout,  QKV = x Wqkv^T + bqkv
//
// R5: faithful port of the verified 256^2 8-phase template (m201) for QKV.
//   Rationale (from R1-R4 counters): 128^2 tiles need ~125 B/cy/CU of staging vs
//   ~56 B/cy/CU L2 path -> capped ~45% util; 256^2 needs ~62 -> only tile that can
//   exceed it, and it forces 1 block/CU -> explicit pipeline required.
//   Schedule per iter (2 K-tiles T0=2i buf0, T1=2i+1 buf1), 8 phases, each:
//     [ds_reads] [1 half-tile stage] sched_barrier(0) s_barrier
//     setprio(1) 16xMFMA setprio(0) [vmcnt @ph4/ph8] s_barrier
//   Stage ledger (proven WAR-safe: every stage issues >=1 barrier after the
//   barrier retiring the last read of its target buffer):
//     ph1: A1(2i+1)  ph3: B0(2i+2)  ph4: B1(2i+2)+vmcnt(4)
//     ph5: A0(2i+2)  ph6: A1(2i+2)  ph7: B0(2i+3)  ph8: B1(2i+3),A0(2i+3)+vmcnt(6)
//   vmcnt(4)@ph4 validates tile 2i+1 (allows B(2i+2) in flight);
//   vmcnt(6)@ph8 validates tile 2i+2 (allows 3 newest half-tiles in flight).
//   Prologue: 7 half-tile stages, vmcnt(6). Tail iter (i=7): stages skipped, vmcnt(0).

typedef __attribute__((ext_vector_type(8))) __bf16 bf16x8;
typedef __attribute__((ext_vector_type(4))) float f32x4;

#define GLOAD16(g, l)                                              \
  __builtin_amdgcn_global_load_lds(                                \
      (const __attribute__((address_space(1))) void*)(g),          \
      (__attribute__((address_space(3))) void*)(l), 16, 0, 0)

#define MFMA16(a, b, c) __builtin_amdgcn_mfma_f32_16x16x32_bf16((a), (b), (c), 0, 0, 0)

// ---------------- fused fp32 -> bf16 convert (x, Wqkv, Wout) ----------------
__global__ __launch_bounds__(256) void cvt3(const float* __restrict__ x,
                                            const float* __restrict__ wqkv,
                                            const float* __restrict__ wout,
                                            __bf16* __restrict__ xb,
                                            __bf16* __restrict__ wqkvb,
                                            __bf16* __restrict__ woutb) {
  const int blk = blockIdx.x;
  const float* src;
  __bf16* dst;
  int i;
  if (blk < 2048) {            // x: 4194304 elems
    src = x; dst = xb; i = (blk * 256 + (int)threadIdx.x) * 8;
  } else if (blk < 3584) {     // Wqkv: 3145728 elems
    src = wqkv; dst = wqkvb; i = ((blk - 2048) * 256 + (int)threadIdx.x) * 8;
  } else {                     // Wout: 1048576 elems
    src = wout; dst = woutb; i = ((blk - 3584) * 256 + (int)threadIdx.x) * 8;
  }
  f32x4 a = *(const f32x4*)(src + i);
  f32x4 b = *(const f32x4*)(src + i + 4);
  bf16x8 o;
  o[0] = (__bf16)a[0]; o[1] = (__bf16)a[1]; o[2] = (__bf16)a[2]; o[3] = (__bf16)a[3];
  o[4] = (__bf16)b[0]; o[5] = (__bf16)b[1]; o[6] = (__bf16)b[2]; o[7] = (__bf16)b[3];
  *(bf16x8*)(dst + i) = o;
}

// ---------------- 256^2 8-phase QKV GEMM (template port) ----------------
// C[m,n] = sum_k A[m,k]*Wqkv[n,k] + bqkv[n];  M=4096, N=3072, K=1024.
// 8 waves (2M x 4N), per-wave 128x64 output. Scatter to Q(*0.125)/K and V-transposed.

#define BAR   __builtin_amdgcn_s_barrier()
#define SBAR0 __builtin_amdgcn_sched_barrier(0)

#define RD_AF(DST, ABASE, ALO)                                                     \
  _Pragma("unroll")                                                                \
  for (int a = 0; a < 4; ++a) {                                                    \
    const int r = ((ALO) + a) * 16 + colL;                                         \
    _Pragma("unroll")                                                              \
    for (int kk = 0; kk < 2; ++kk)                                                 \
      DST[a][kk] = *(const bf16x8*)((ABASE) + r * 128 +                            \
                                    ((((kk << 2) + g) ^ (r & 7)) << 4));           \
  }

#define RD_BF(DST, BBASE, NLO)                                                     \
  _Pragma("unroll")                                                                \
  for (int nb = 0; nb < 2; ++nb) {                                                 \
    const int r = ((wn & 1) << 6) + ((NLO) + nb) * 16 + colL;                      \
    _Pragma("unroll")                                                              \
    for (int kk = 0; kk < 2; ++kk)                                                 \
      DST[nb][kk] = *(const bf16x8*)((BBASE) + r * 128 +                           \
                                     ((((kk << 2) + g) ^ (r & 7)) << 4));          \
  }

#define QUADM(ALO, NLO, AF, BF)                                                    \
  __builtin_amdgcn_s_setprio(1);                                                   \
  _Pragma("unroll")                                                                \
  for (int a = 0; a < 4; ++a)                                                      \
    _Pragma("unroll")                                                              \
    for (int nb = 0; nb < 2; ++nb) {                                               \
      acc[(ALO) + a][(NLO) + nb] =                                                 \
          MFMA16(AF[a][0], BF[nb][0], acc[(ALO) + a][(NLO) + nb]);                 \
      acc[(ALO) + a][(NLO) + nb] =                                                 \
          MFMA16(AF[a][1], BF[nb][1], acc[(ALO) + a][(NLO) + nb]);                 \
    }                                                                              \
  __builtin_amdgcn_s_setprio(0);

__global__ __launch_bounds__(512, 2) void gemm256_qkv(
    const __bf16* __restrict__ A, const __bf16* __restrict__ Bw,
    const float* __restrict__ bias,
    __bf16* __restrict__ qo, __bf16* __restrict__ ko, __bf16* __restrict__ vt) {
  constexpr int K = 1024;
  __shared__ __align__(16) unsigned char AsBuf[2][32768];  // [buf][half0|half1], 128Bx128r per half
  __shared__ __align__(16) unsigned char BsBuf[2][32768];
  const int tid = threadIdx.x;
  const int lane = tid & 63;
  const int wid = tid >> 6;               // 0..7
  const int wm = wid >> 2, wn = wid & 3;  // 2M x 4N
  const int colL = lane & 15, g = lane >> 4;

  // XCD-aware swizzle: 192 blocks, 24/XCD (192%8==0 -> bijective)
  int s = blockIdx.x;
  s = (s & 7) * 24 + (s >> 3);
  const int m0 = (s / 12) * 256, n0 = (s % 12) * 256;

  const __bf16* Ap0 = A + (size_t)m0 * K;
  const __bf16* Ap1 = A + (size_t)(m0 + 128) * K;
  const __bf16* Bp0 = Bw + (size_t)n0 * K;
  const __bf16* Bp1 = Bw + (size_t)(n0 + 128) * K;

  // one half-tile (128 rows x 64 cols = 16KB): linear LDS dest, inv-swizzled source
  auto stage = [&](const __bf16* src, unsigned char* lds, int k0) {
#pragma unroll
    for (int it = 0; it < 2; ++it) {
      int c = tid + (it << 9);
      int row = c >> 3, pp = c & 7;
      int q = pp ^ (row & 7);
      GLOAD16(src + (size_t)row * K + k0 + (q << 3), lds + c * 16);
    }
  };

  f32x4 acc[8][4] = {};

  const unsigned char* A0b = AsBuf[0] + (wm << 14);
  const unsigned char* A1b = AsBuf[1] + (wm << 14);
  const unsigned char* B0b = BsBuf[0] + ((wn >> 1) << 14);
  const unsigned char* B1b = BsBuf[1] + ((wn >> 1) << 14);

  // prologue: tile0 {A0,A1,B0,B1}, tile1 {B0,B1,A0}; A1(1) staged at iter0-ph1
  stage(Ap0, AsBuf[0], 0);
  stage(Ap1, AsBuf[0] + 16384, 0);
  stage(Bp0, BsBuf[0], 0);
  stage(Bp1, BsBuf[0] + 16384, 0);
  stage(Bp0, BsBuf[1], 64);
  stage(Bp1, BsBuf[1] + 16384, 64);
  stage(Ap0, AsBuf[1], 64);
  asm volatile("s_waitcnt vmcnt(6)" ::: "memory");  // tile0 landed; 3 stages in flight
  BAR;

  for (int i = 0; i < 8; ++i) {
    const bool lst = (i == 7);
    const int kc1 = (2 * i + 1) << 6;
    const int kc2 = (2 * i + 2) << 6;
    const int kc3 = (2 * i + 3) << 6;
    bf16x8 afA[4][2], afB[4][2], bfA[2][2], bfB[2][2];

    // ph1: read af[0..3](T0), bf[0..1](T0); stage A1(T1)
    RD_AF(afA, A0b, 0);
    RD_BF(bfA, B0b, 0);
    stage(Ap1, AsBuf[1] + 16384, kc1);
    SBAR0; BAR;
    QUADM(0, 0, afA, bfA);
    BAR;

    // ph2: read bf[2..3](T0)
    RD_BF(bfB, B0b, 2);
    SBAR0; BAR;
    QUADM(0, 2, afA, bfB);
    BAR;

    // ph3: read af[4..7](T0); stage B0(2i+2)  [bufB0 retired at ph2-end]
    RD_AF(afB, A0b, 4);
    if (!lst) stage(Bp0, BsBuf[0], kc2);
    SBAR0; BAR;
    QUADM(4, 2, afB, bfB);
    BAR;

    // ph4: stage B1(2i+2); vmcnt validates tile 2i+1
    if (!lst) stage(Bp1, BsBuf[0] + 16384, kc2);
    SBAR0; BAR;
    QUADM(4, 0, afB, bfA);
    if (!lst) asm volatile("s_waitcnt vmcnt(4)" ::: "memory");
    else      asm volatile("s_waitcnt vmcnt(0)" ::: "memory");
    BAR;

    // ph5: read af[0..3](T1), bf[0..1](T1); stage A0(2i+2)  [bufA0 retired ph3-end]
    RD_AF(afA, A1b, 0);
    RD_BF(bfA, B1b, 0);
    if (!lst) stage(Ap0, AsBuf[0], kc2);
    SBAR0; BAR;
    QUADM(0, 0, afA, bfA);
    BAR;

    // ph6: read bf[2..3](T1); stage A1(2i+2)
    RD_BF(bfB, B1b, 2);
    if (!lst) stage(Ap1, AsBuf[0] + 16384, kc2);
    SBAR0; BAR;
    QUADM(0, 2, afA, bfB);
    BAR;

    // ph7: read af[4..7](T1); stage B0(2i+3)  [bufB1 retired ph6-end]
    RD_AF(afB, A1b, 4);
    if (!lst) stage(Bp0, BsBuf[1], kc3);
    SBAR0; BAR;
    QUADM(4, 2, afB, bfB);
    BAR;

    // ph8: stage B1(2i+3), A0(2i+3)  [bufA1 retired ph7-end]; vmcnt validates 2i+2
    if (!lst) { stage(Bp1, BsBuf[1] + 16384, kc3); stage(Ap0, AsBuf[1], kc3); }
    SBAR0; BAR;
    QUADM(4, 0, afB, bfA);
    if (!lst) asm volatile("s_waitcnt vmcnt(6)" ::: "memory");
    else      asm volatile("s_waitcnt vmcnt(0)" ::: "memory");
    BAR;
  }

  // epilogue: C/D layout col=lane&15, row=(lane>>4)*4+reg; scatter Q/K, V transposed
#pragma unroll
  for (int ni = 0; ni < 4; ++ni) {
    const int Cn = n0 + wn * 64 + ni * 16 + colL;
    const float bv = bias[Cn];
    const int sx = Cn >> 10, h = (Cn >> 6) & 15, d = Cn & 63;
    const float mul = (sx == 0) ? 0.125f : 1.0f;  // fold SCALE into Q (exact pow2)
#pragma unroll
    for (int mi = 0; mi < 8; ++mi) {
#pragma unroll
      for (int j = 0; j < 4; ++j) {
        const int Rm = m0 + wm * 128 + mi * 16 + (g << 2) + j;
        const int bb = Rm >> 11, tt = Rm & 2047;
        const float v = (acc[mi][ni][j] + bv) * mul;
        if (sx == 2) {
          vt[(((size_t)bb * 16 + h) * 64 + d) * 2048 + tt] = (__bf16)v;
        } else {
          __bf16* dst = (sx == 0) ? qo : ko;
          dst[(((size_t)bb * 16 + h) * 2048 + tt) * 64 + d] = (__bf16)v;
        }
      }
    }
  }
}

// ---------------- 128^2 m97-style GEMM (out-proj): C = A*Bw^T + bias, fp32 out ----
__global__ __launch_bounds__(256) void gemm_bt_out(
    const __bf16* __restrict__ A, const __bf16* __restrict__ Bw,
    const float* __restrict__ bias, int M, int N, int K,
    float* __restrict__ outF) {
  __shared__ __align__(16) unsigned char As[128 * 128];
  __shared__ __align__(16) unsigned char Bs[128 * 128];
  const int tid = threadIdx.x;
  const int lane = tid & 63;
  const int wid = tid >> 6;
  const int wr = wid >> 1, wc = wid & 1;
  const int colL = lane & 15, g = lane >> 4;
  const int m0 = blockIdx.x * 128, n0 = blockIdx.y * 128;

  f32x4 acc[4][4] = {};

  const int nK = K >> 6;
  for (int ks = 0; ks < nK; ++ks) {
    const int k0 = ks << 6;
    __syncthreads();
#pragma unroll
    for (int it = 0; it < 4; ++it) {
      int c = tid + (it << 8);
      int row = c >> 3, p = c & 7;
      int q = p ^ (row & 7);
      GLOAD16(A + (size_t)(m0 + row) * K + (k0 + (q << 3)), As + c * 16);
      GLOAD16(Bw + (size_t)(n0 + row) * K + (k0 + (q << 3)), Bs + c * 16);
    }
    __syncthreads();
#pragma unroll
    for (int kk = 0; kk < 2; ++kk) {
      bf16x8 af[4], bf[4];
      const int slot = (kk << 2) + g;
#pragma unroll
      for (int mi = 0; mi < 4; ++mi) {
        int r = (wr << 6) + (mi << 4) + colL;
        af[mi] = *(const bf16x8*)(As + r * 128 + ((slot ^ (r & 7)) << 4));
      }
#pragma unroll
      for (int ni = 0; ni < 4; ++ni) {
        int r = (wc << 6) + (ni << 4) + colL;
        bf[ni] = *(const bf16x8*)(Bs + r * 128 + ((slot ^ (r & 7)) << 4));
      }
#pragma unroll
      for (int mi = 0; mi < 4; ++mi)
#pragma unroll
        for (int ni = 0; ni < 4; ++ni)
          acc[mi][ni] = MFMA16(af[mi], bf[ni], acc[mi][ni]);
    }
  }

#pragma unroll
  for (int ni = 0; ni < 4; ++ni) {
    const int Cn = n0 + (wc << 6) + (ni << 4) + colL;
    const float bv = bias[Cn];
#pragma unroll
    for (int mi = 0; mi < 4; ++mi) {
#pragma unroll
      for (int j = 0; j < 4; ++j) {
        const int Rm = m0 + (wr << 6) + (mi << 4) + (g << 2) + j;
        outF[(size_t)Rm * N + Cn] = acc[mi][ni][j] + bv;
      }
    }
  }
}

// ---------------- windowed attention ----------------
__global__ __launch_bounds__(256) void attn_win(const __bf16* __restrict__ Qb,
                                                const __bf16* __restrict__ Kb,
                                                const __bf16* __restrict__ Vt,
                                                __bf16* __restrict__ Ob) {
  const int bh = blockIdx.x >> 5;
  const int qb = blockIdx.x & 31;
  const int b = bh >> 4, h = bh & 15;
  __shared__ __align__(16) unsigned char Qs[64 * 128];
  __shared__ __align__(16) unsigned char Ks[128 * 128];
  __shared__ __align__(16) unsigned char Vs[64 * 256];
  __shared__ __align__(16) unsigned char Ps[4 * 16 * 272];
  const int tid = threadIdx.x;
  const int lane = tid & 63;
  const int w = tid >> 6;
  const int colL = lane & 15, g = lane >> 4;
  const __bf16* Qg = Qb + (size_t)bh * 2048 * 64;
  const __bf16* Kg = Kb + (size_t)bh * 2048 * 64;
  const __bf16* Vg = Vt + (size_t)bh * 64 * 2048;
  const int t0 = qb * 64 - 64;

#pragma unroll
  for (int it = 0; it < 2; ++it) {
    int c = tid + (it << 8);
    int r = c >> 3, p = c & 7, q = p ^ (r & 7);
    GLOAD16(Qg + (size_t)(qb * 64 + r) * 64 + (q << 3), Qs + c * 16);
  }
#pragma unroll
  for (int it = 0; it < 4; ++it) {
    int c = tid + (it << 8);
    int r = c >> 3, p = c & 7, q = p ^ (r & 7);
    int tok = t0 + r;
    tok = tok < 0 ? 0 : tok;
    GLOAD16(Kg + (size_t)tok * 64 + (q << 3), Ks + c * 16);
  }
#pragma unroll
  for (int it = 0; it < 4; ++it) {
    int c = tid + (it << 8);
    int r = c >> 4, p = c & 15, q = p ^ (r & 7);
    int tk = t0 + (q << 3);
    tk = tk < 0 ? 0 : tk;
    GLOAD16(Vg + (size_t)r * 2048 + tk, Vs + c * 16);
  }
  __syncthreads();

  f32x4 sc[8] = {};
  bf16x8 qf[2];
#pragma unroll
  for (int kk = 0; kk < 2; ++kk) {
    int r = (w << 4) + colL;
    int slot = (kk << 2) + g;
    qf[kk] = *(const bf16x8*)(Qs + r * 128 + ((slot ^ (r & 7)) << 4));
  }
#pragma unroll
  for (int ni = 0; ni < 8; ++ni) {
#pragma unroll
    for (int kk = 0; kk < 2; ++kk) {
      int r = (ni << 4) + colL;
      int slot = (kk << 2) + g;
      bf16x8 kf = *(const bf16x8*)(Ks + r * 128 + ((slot ^ (r & 7)) << 4));
      sc[ni] = MFMA16(qf[kk], kf, sc[ni]);
    }
  }

  float mx[4], sm[4];
#pragma unroll
  for (int j = 0; j < 4; ++j) mx[j] = -3.0e38f;
#pragma unroll
  for (int ni = 0; ni < 8; ++ni) {
#pragma unroll
    for (int j = 0; j < 4; ++j) {
      const int qi = (w << 4) + (g << 2) + j;
      const int ki = (ni << 4) + colL;
      const bool valid = (ki > qi) && (ki <= qi + 64) && (qb > 0 || ki >= 64);
      if (!valid) sc[ni][j] = -3.0e38f;
      mx[j] = fmaxf(mx[j], sc[ni][j]);
    }
  }
#pragma unroll
  for (int j = 0; j < 4; ++j) {
    mx[j] = fmaxf(mx[j], __shfl_xor(mx[j], 1));
    mx[j] = fmaxf(mx[j], __shfl_xor(mx[j], 2));
    mx[j] = fmaxf(mx[j], __shfl_xor(mx[j], 4));
    mx[j] = fmaxf(mx[j], __shfl_xor(mx[j], 8));
    sm[j] = 0.0f;
  }
  unsigned char* ps = Ps + w * (16 * 272);
#pragma unroll
  for (int ni = 0; ni < 8; ++ni) {
#pragma unroll
    for (int j = 0; j < 4; ++j) {
      float p = __expf(sc[ni][j] - mx[j]);
      sm[j] += p;
      *(__bf16*)(ps + ((g << 2) + j) * 272 + (((ni << 4) + colL) << 1)) = (__bf16)p;
    }
  }
#pragma unroll
  for (int j = 0; j < 4; ++j) {
    sm[j] += __shfl_xor(sm[j], 1);
    sm[j] += __shfl_xor(sm[j], 2);
    sm[j] += __shfl_xor(sm[j], 4);
    sm[j] += __shfl_xor(sm[j], 8);
  }
  __syncthreads();

  f32x4 o[4] = {};
#pragma unroll
  for (int step = 0; step < 4; ++step) {
    bf16x8 pf = *(const bf16x8*)(ps + colL * 272 + (step << 6) + (g << 4));
#pragma unroll
    for (int dt = 0; dt < 4; ++dt) {
      int r = (dt << 4) + colL;
      int slot = (step << 2) + g;
      bf16x8 vf = *(const bf16x8*)(Vs + r * 256 + ((slot ^ (r & 7)) << 4));
      o[dt] = MFMA16(pf, vf, o[dt]);
    }
  }

  float rinv[4];
#pragma unroll
  for (int j = 0; j < 4; ++j) rinv[j] = 1.0f / sm[j];
#pragma unroll
  for (int dt = 0; dt < 4; ++dt) {
#pragma unroll
    for (int j = 0; j < 4; ++j) {
      const int t = qb * 64 + (w << 4) + (g << 2) + j;
      Ob[((size_t)b * 2048 + t) * 1024 + h * 64 + (dt << 4) + colL] =
          (__bf16)(o[dt][j] * rinv[j]);
    }
  }
}

extern "C" void kernel_launch(void* const* d_in, const int* in_sizes, int n_in,
                              void* d_out, int out_size, void* d_ws, size_t ws_size,
                              hipStream_t stream) {
  const float* x = (const float*)d_in[0];     // [2,2048,1024]
  const float* Wqkv = (const float*)d_in[1];  // [3072,1024]
  const float* bqkv = (const float*)d_in[2];  // [3072]
  const float* Wout = (const float*)d_in[3];  // [1024,1024]
  const float* bout = (const float*)d_in[4];  // [1024]
  float* out = (float*)d_out;                 // [2,2048,1024] fp32

  __bf16* xb = (__bf16*)d_ws;             // 4194304
  __bf16* Wqkvb = xb + 4194304;           // 3145728
  __bf16* Woutb = Wqkvb + 3145728;        // 1048576
  __bf16* Qb = Woutb + 1048576;           // 4194304 each: [B,H,2048,64]
  __bf16* Kb = Qb + 4194304;
  __bf16* Vtb = Kb + 4194304;             // [B,H,64,2048] (written transposed by gemm)
  __bf16* AOb = Vtb + 4194304;            // attn out [B,2048,1024]

  cvt3<<<4096, 256, 0, stream>>>(x, Wqkv, Wout, xb, Wqkvb, Woutb);
  gemm256_qkv<<<192, 512, 0, stream>>>(xb, Wqkvb, bqkv, Qb, Kb, Vtb);
  attn_win<<<1024, 256, 0, stream>>>(Qb, Kb, Vtb, AOb);
  gemm_bt_out<<<dim3(32, 8), 256, 0, stream>>>(AOb, Woutb, bout, 4096, 1024, 1024, out);
}

// Round 6
// 90.420 us; speedup vs baseline: 1.2217x; 1.2217x over previous
//
#include <hip/hip_runtime.h>
#include <hip/hip_bf16.h>

// LocalCausalAttention: B=2, N=2048, D=1024, H=16, DH=64, WINDOW=64
// out = ( softmax(mask(QK^T*0.125)) V ) Wout^T + bout,  QKV = x Wqkv^T + bqkv
//
// R6: dbuf-BK32 GEMM = multi-block TLP (128^2 tile, 32KB LDS, 3+ blocks/CU like R1)
//     WITHOUT the per-step vmcnt drain (R1's known ~fixed cost):
//   per step t: {8x ds_read_b128 ; 16 MFMA ; lgkmcnt(0) ; bar ;
//                stage tile t+2 -> buf[t&1] (4 gloads) ; vmcnt(4) ; bar}
//   vmcnt(4) validates tile t+1 (staged one full step earlier); tile t+2 stays
//   in flight. lgkmcnt(0) before bar1 guarantees all LDS reads executed before
//   any wave's DMA (global_load_lds) can overwrite the buffer (WAR ledger).
//   LDS layout: 128 rows x 64B packed 2 rows/128B-line; slot s6 = ((row&1)<<2|g)
//   XOR (line&7) -> verified 8-distinct-banks per lane-octet on ds_read_b128,
//   and exact involution on the stage side (inverse-swizzled global source).
//   T1 XCD chunking (n-fastest): QKV 768 blocks = 96/XCD, outproj 256 = 32/XCD.
// Scoreboard so far (QKV): R1 2-barrier 55us > R2/R3/R5 deep-phase 57-75us.

typedef __attribute__((ext_vector_type(8))) __bf16 bf16x8;
typedef __attribute__((ext_vector_type(4))) float f32x4;

#define GLOAD16(g, l)                                              \
  __builtin_amdgcn_global_load_lds(                                \
      (const __attribute__((address_space(1))) void*)(g),          \
      (__attribute__((address_space(3))) void*)(l), 16, 0, 0)

#define MFMA16(a, b, c) __builtin_amdgcn_mfma_f32_16x16x32_bf16((a), (b), (c), 0, 0, 0)

// ---------------- fused fp32 -> bf16 convert (x, Wqkv, Wout) ----------------
__global__ __launch_bounds__(256) void cvt3(const float* __restrict__ x,
                                            const float* __restrict__ wqkv,
                                            const float* __restrict__ wout,
                                            __bf16* __restrict__ xb,
                                            __bf16* __restrict__ wqkvb,
                                            __bf16* __restrict__ woutb) {
  const int blk = blockIdx.x;
  const float* src;
  __bf16* dst;
  int i;
  if (blk < 2048) {            // x: 4194304 elems
    src = x; dst = xb; i = (blk * 256 + (int)threadIdx.x) * 8;
  } else if (blk < 3584) {     // Wqkv: 3145728 elems
    src = wqkv; dst = wqkvb; i = ((blk - 2048) * 256 + (int)threadIdx.x) * 8;
  } else {                     // Wout: 1048576 elems
    src = wout; dst = woutb; i = ((blk - 3584) * 256 + (int)threadIdx.x) * 8;
  }
  f32x4 a = *(const f32x4*)(src + i);
  f32x4 b = *(const f32x4*)(src + i + 4);
  bf16x8 o;
  o[0] = (__bf16)a[0]; o[1] = (__bf16)a[1]; o[2] = (__bf16)a[2]; o[3] = (__bf16)a[3];
  o[4] = (__bf16)b[0]; o[5] = (__bf16)b[1]; o[6] = (__bf16)b[2]; o[7] = (__bf16)b[3];
  *(bf16x8*)(dst + i) = o;
}

// ---------------- 128^2 BK=32 double-buffered GEMM ----------------
// C[m,n] = sum_k A[m,k]*Bw[n,k] + bias[n].  4 waves (2x2), per-wave 64x64.
// LDS 32KB total: [buf0: A 8KB | B 8KB][buf1: A 8KB | B 8KB].
// MODE 0: scatter bf16 to Q(*0.125)/K/V [B,H,2048,64].  MODE 1: fp32 out + bias.
template <int MODE>
__global__ __launch_bounds__(256) void gemm_db(
    const __bf16* __restrict__ A, const __bf16* __restrict__ Bw,
    const float* __restrict__ bias, int M, int N, int K,
    float* __restrict__ outF,
    __bf16* __restrict__ qo, __bf16* __restrict__ ko, __bf16* __restrict__ vo,
    int nbn, int chunk) {
  __shared__ __align__(16) unsigned char Ls[32768];
  const int tid = threadIdx.x;
  const int lane = tid & 63;
  const int wid = tid >> 6;
  const int wr = wid >> 1, wc = wid & 1;
  const int colL = lane & 15, g = lane >> 4;

  // T1: XCD chunking (grid %8 == 0 -> bijective). n varies fastest inside chunk.
  int s = (int)blockIdx.x;
  s = (s & 7) * chunk + (s >> 3);
  const int m0 = (s / nbn) * 128, n0 = (s % nbn) * 128;

  const __bf16* Ap = A + (size_t)m0 * K;
  const __bf16* Bp = Bw + (size_t)n0 * K;

  // stage one matrix half-step (128 rows x 32 cols = 8KB) into lds:
  // linear LDS dest c*16; line L=c>>3, s6=c&7; u=s6^(L&7) -> row=2L+(u>>2), p=u&3.
  auto stage2 = [&](const __bf16* src, unsigned char* lds, int k0) {
#pragma unroll
    for (int it = 0; it < 2; ++it) {
      int c = tid + (it << 8);       // 0..511
      int L = c >> 3, s6 = c & 7;
      int u = s6 ^ (L & 7);
      int row = (L << 1) | (u >> 2), p = u & 3;
      GLOAD16(src + (size_t)row * K + k0 + (p << 3), lds + c * 16);
    }
  };

  f32x4 acc[4][4] = {};

  // prologue: tiles 0,1 into bufs 0,1
  stage2(Ap, Ls, 0);
  stage2(Bp, Ls + 8192, 0);
  stage2(Ap, Ls + 16384, 32);
  stage2(Bp, Ls + 24576, 32);
  asm volatile("s_waitcnt vmcnt(4)" ::: "memory");  // tile0 landed; tile1 in flight
  __builtin_amdgcn_s_barrier();

  const int nT = K >> 5;  // 32 steps
  for (int t = 0; t < nT; ++t) {
    const unsigned char* Ab = Ls + (t & 1) * 16384;
    const unsigned char* Bb = Ab + 8192;
    bf16x8 af[4], bf[4];
#pragma unroll
    for (int mi = 0; mi < 4; ++mi) {
      const int r = (wr << 6) + (mi << 4) + colL;
      af[mi] = *(const bf16x8*)(Ab + (r >> 1) * 128 +
                                (((((r & 1) << 2) | g) ^ ((r >> 1) & 7)) << 4));
    }
#pragma unroll
    for (int ni = 0; ni < 4; ++ni) {
      const int r = (wc << 6) + (ni << 4) + colL;
      bf[ni] = *(const bf16x8*)(Bb + (r >> 1) * 128 +
                                (((((r & 1) << 2) | g) ^ ((r >> 1) & 7)) << 4));
    }
#pragma unroll
    for (int mi = 0; mi < 4; ++mi)
#pragma unroll
      for (int ni = 0; ni < 4; ++ni)
        acc[mi][ni] = MFMA16(af[mi], bf[ni], acc[mi][ni]);
    // all this wave's ds_reads executed before anyone may DMA-overwrite buf[cur]
    asm volatile("s_waitcnt lgkmcnt(0)" ::: "memory");
    __builtin_amdgcn_s_barrier();
    if (t < nT - 2) {
      const int kn = (t + 2) << 5;
      unsigned char* dst = Ls + (t & 1) * 16384;  // overwrite just-retired buffer
      stage2(Ap, dst, kn);
      stage2(Bp, dst + 8192, kn);
      // in flight: tile t+1 (4) + tile t+2 (4); retire oldest 4 -> t+1 validated
      asm volatile("s_waitcnt vmcnt(4)" ::: "memory");
    } else {
      asm volatile("s_waitcnt vmcnt(0)" ::: "memory");  // tail: drain last tile
    }
    __builtin_amdgcn_s_barrier();
  }

  // epilogue: C/D layout col=lane&15, row=(lane>>4)*4+reg (m89-verified)
#pragma unroll
  for (int ni = 0; ni < 4; ++ni) {
    const int Cn = n0 + (wc << 6) + (ni << 4) + colL;
    const float bv = bias[Cn];
    if (MODE == 0) {
      const int sx = Cn >> 10, h = (Cn >> 6) & 15, d = Cn & 63;
      __bf16* dst = (sx == 0) ? qo : (sx == 1 ? ko : vo);
      const float mul = (sx == 0) ? 0.125f : 1.0f;  // fold SCALE into Q (exact pow2)
#pragma unroll
      for (int mi = 0; mi < 4; ++mi) {
#pragma unroll
        for (int j = 0; j < 4; ++j) {
          const int Rm = m0 + (wr << 6) + (mi << 4) + (g << 2) + j;
          const int bb = Rm >> 11, tt = Rm & 2047;
          dst[(((size_t)bb * 16 + h) * 2048 + tt) * 64 + d] =
              (__bf16)((acc[mi][ni][j] + bv) * mul);
        }
      }
    } else {
#pragma unroll
      for (int mi = 0; mi < 4; ++mi) {
#pragma unroll
        for (int j = 0; j < 4; ++j) {
          const int Rm = m0 + (wr << 6) + (mi << 4) + (g << 2) + j;
          outF[(size_t)Rm * N + Cn] = acc[mi][ni][j] + bv;
        }
      }
    }
  }
}

// ---------------- V [bh, t, 64] -> Vt [bh, 64, t] (64x64 tiles via LDS) ----------------
__global__ __launch_bounds__(256) void transpose_v(const __bf16* __restrict__ Vb,
                                                   __bf16* __restrict__ Vt) {
  const int blk = blockIdx.x;
  const int bh = blk >> 5;
  const int t0 = (blk & 31) << 6;
  __shared__ __align__(16) __bf16 ts[64][72];
  const int tid = threadIdx.x;
  const __bf16* src = Vb + ((size_t)bh * 2048 + t0) * 64;
#pragma unroll
  for (int it = 0; it < 2; ++it) {
    int c = tid + (it << 8);
    int r = c >> 3, q8 = (c & 7) << 3;
    *(bf16x8*)&ts[r][q8] = *(const bf16x8*)(src + r * 64 + q8);
  }
  __syncthreads();
  __bf16* dst = Vt + (size_t)bh * 64 * 2048 + t0;
#pragma unroll
  for (int it = 0; it < 2; ++it) {
    int c = tid + (it << 8);
    int d = c >> 3, j8 = (c & 7) << 3;
    bf16x8 o;
#pragma unroll
    for (int e = 0; e < 8; ++e) o[e] = ts[j8 + e][d];
    *(bf16x8*)(dst + (size_t)d * 2048 + j8) = o;
  }
}

// ---------------- windowed attention ----------------
__global__ __launch_bounds__(256) void attn_win(const __bf16* __restrict__ Qb,
                                                const __bf16* __restrict__ Kb,
                                                const __bf16* __restrict__ Vt,
                                                __bf16* __restrict__ Ob) {
  const int bh = blockIdx.x >> 5;
  const int qb = blockIdx.x & 31;
  const int b = bh >> 4, h = bh & 15;
  __shared__ __align__(16) unsigned char Qs[64 * 128];
  __shared__ __align__(16) unsigned char Ks[128 * 128];
  __shared__ __align__(16) unsigned char Vs[64 * 256];
  __shared__ __align__(16) unsigned char Ps[4 * 16 * 272];
  const int tid = threadIdx.x;
  const int lane = tid & 63;
  const int w = tid >> 6;
  const int colL = lane & 15, g = lane >> 4;
  const __bf16* Qg = Qb + (size_t)bh * 2048 * 64;
  const __bf16* Kg = Kb + (size_t)bh * 2048 * 64;
  const __bf16* Vg = Vt + (size_t)bh * 64 * 2048;
  const int t0 = qb * 64 - 64;

#pragma unroll
  for (int it = 0; it < 2; ++it) {
    int c = tid + (it << 8);
    int r = c >> 3, p = c & 7, q = p ^ (r & 7);
    GLOAD16(Qg + (size_t)(qb * 64 + r) * 64 + (q << 3), Qs + c * 16);
  }
#pragma unroll
  for (int it = 0; it < 4; ++it) {
    int c = tid + (it << 8);
    int r = c >> 3, p = c & 7, q = p ^ (r & 7);
    int tok = t0 + r;
    tok = tok < 0 ? 0 : tok;
    GLOAD16(Kg + (size_t)tok * 64 + (q << 3), Ks + c * 16);
  }
#pragma unroll
  for (int it = 0; it < 4; ++it) {
    int c = tid + (it << 8);
    int r = c >> 4, p = c & 15, q = p ^ (r & 7);
    int tk = t0 + (q << 3);
    tk = tk < 0 ? 0 : tk;
    GLOAD16(Vg + (size_t)r * 2048 + tk, Vs + c * 16);
  }
  __syncthreads();

  f32x4 sc[8] = {};
  bf16x8 qf[2];
#pragma unroll
  for (int kk = 0; kk < 2; ++kk) {
    int r = (w << 4) + colL;
    int slot = (kk << 2) + g;
    qf[kk] = *(const bf16x8*)(Qs + r * 128 + ((slot ^ (r & 7)) << 4));
  }
#pragma unroll
  for (int ni = 0; ni < 8; ++ni) {
#pragma unroll
    for (int kk = 0; kk < 2; ++kk) {
      int r = (ni << 4) + colL;
      int slot = (kk << 2) + g;
      bf16x8 kf = *(const bf16x8*)(Ks + r * 128 + ((slot ^ (r & 7)) << 4));
      sc[ni] = MFMA16(qf[kk], kf, sc[ni]);
    }
  }

  float mx[4], sm[4];
#pragma unroll
  for (int j = 0; j < 4; ++j) mx[j] = -3.0e38f;
#pragma unroll
  for (int ni = 0; ni < 8; ++ni) {
#pragma unroll
    for (int j = 0; j < 4; ++j) {
      const int qi = (w << 4) + (g << 2) + j;
      const int ki = (ni << 4) + colL;
      const bool valid = (ki > qi) && (ki <= qi + 64) && (qb > 0 || ki >= 64);
      if (!valid) sc[ni][j] = -3.0e38f;
      mx[j] = fmaxf(mx[j], sc[ni][j]);
    }
  }
#pragma unroll
  for (int j = 0; j < 4; ++j) {
    mx[j] = fmaxf(mx[j], __shfl_xor(mx[j], 1));
    mx[j] = fmaxf(mx[j], __shfl_xor(mx[j], 2));
    mx[j] = fmaxf(mx[j], __shfl_xor(mx[j], 4));
    mx[j] = fmaxf(mx[j], __shfl_xor(mx[j], 8));
    sm[j] = 0.0f;
  }
  unsigned char* ps = Ps + w * (16 * 272);
#pragma unroll
  for (int ni = 0; ni < 8; ++ni) {
#pragma unroll
    for (int j = 0; j < 4; ++j) {
      float p = __expf(sc[ni][j] - mx[j]);
      sm[j] += p;
      *(__bf16*)(ps + ((g << 2) + j) * 272 + (((ni << 4) + colL) << 1)) = (__bf16)p;
    }
  }
#pragma unroll
  for (int j = 0; j < 4; ++j) {
    sm[j] += __shfl_xor(sm[j], 1);
    sm[j] += __shfl_xor(sm[j], 2);
    sm[j] += __shfl_xor(sm[j], 4);
    sm[j] += __shfl_xor(sm[j], 8);
  }
  __syncthreads();

  f32x4 o[4] = {};
#pragma unroll
  for (int step = 0; step < 4; ++step) {
    bf16x8 pf = *(const bf16x8*)(ps + colL * 272 + (step << 6) + (g << 4));
#pragma unroll
    for (int dt = 0; dt < 4; ++dt) {
      int r = (dt << 4) + colL;
      int slot = (step << 2) + g;
      bf16x8 vf = *(const bf16x8*)(Vs + r * 256 + ((slot ^ (r & 7)) << 4));
      o[dt] = MFMA16(pf, vf, o[dt]);
    }
  }

  float rinv[4];
#pragma unroll
  for (int j = 0; j < 4; ++j) rinv[j] = 1.0f / sm[j];
#pragma unroll
  for (int dt = 0; dt < 4; ++dt) {
#pragma unroll
    for (int j = 0; j < 4; ++j) {
      const int t = qb * 64 + (w << 4) + (g << 2) + j;
      Ob[((size_t)b * 2048 + t) * 1024 + h * 64 + (dt << 4) + colL] =
          (__bf16)(o[dt][j] * rinv[j]);
    }
  }
}

extern "C" void kernel_launch(void* const* d_in, const int* in_sizes, int n_in,
                              void* d_out, int out_size, void* d_ws, size_t ws_size,
                              hipStream_t stream) {
  const float* x = (const float*)d_in[0];     // [2,2048,1024]
  const float* Wqkv = (const float*)d_in[1];  // [3072,1024]
  const float* bqkv = (const float*)d_in[2];  // [3072]
  const float* Wout = (const float*)d_in[3];  // [1024,1024]
  const float* bout = (const float*)d_in[4];  // [1024]
  float* out = (float*)d_out;                 // [2,2048,1024] fp32

  __bf16* xb = (__bf16*)d_ws;             // 4194304
  __bf16* Wqkvb = xb + 4194304;           // 3145728
  __bf16* Woutb = Wqkvb + 3145728;        // 1048576
  __bf16* Qb = Woutb + 1048576;           // 4194304 each: [B,H,2048,64]
  __bf16* Kb = Qb + 4194304;
  __bf16* Vb = Kb + 4194304;
  __bf16* Vtb = Vb + 4194304;             // [B,H,64,2048]
  __bf16* AOb = Vtb + 4194304;            // attn out [B,2048,1024]

  cvt3<<<4096, 256, 0, stream>>>(x, Wqkv, Wout, xb, Wqkvb, Woutb);
  gemm_db<0><<<768, 256, 0, stream>>>(xb, Wqkvb, bqkv, 4096, 3072, 1024,
                                      nullptr, Qb, Kb, Vb, 24, 96);
  transpose_v<<<1024, 256, 0, stream>>>(Vb, Vtb);
  attn_win<<<1024, 256, 0, stream>>>(Qb, Kb, Vtb, AOb);
  gemm_db<1><<<256, 256, 0, stream>>>(AOb, Woutb, bout, 4096, 1024, 1024,
                                      out, nullptr, nullptr, nullptr, 8, 32);
}